// Round 1
// baseline (601.686 us; speedup 1.0000x reference)
//
#include <hip/hip_runtime.h>
#include <hip/hip_bf16.h>
#include <math.h>

#define B_ 4
#define S_ 1024
#define D_ 1024
#define H_ 16
#define DK_ 64

typedef short bf16x8 __attribute__((ext_vector_type(8)));
typedef float f32x4 __attribute__((ext_vector_type(4)));

#define MFMA(a, b, c) __builtin_amdgcn_mfma_f32_16x16x32_bf16(a, b, c, 0, 0, 0)

// async global->LDS, 16B per lane. Effective LDS dest = wave-uniform base + lane*16.
#define GLDS(gp, lp)                                                        \
    __builtin_amdgcn_global_load_lds(                                       \
        (const __attribute__((address_space(1))) void*)(const void*)(gp),   \
        (__attribute__((address_space(3))) void*)(void*)(lp), 16, 0, 0)

static __device__ __forceinline__ unsigned short f2bf(float f) {
    __hip_bfloat16 h = __float2bfloat16(f);
    return *reinterpret_cast<unsigned short*>(&h);
}
static __device__ __forceinline__ float bf2f(unsigned short u) {
    unsigned int x = ((unsigned int)u) << 16;
    union { unsigned int i; float f; } c; c.i = x; return c.f;
}

// ---------------------------------------------------------------------------
// fused f32->bf16 converts: 3 activations (12288 blocks) + 4 weights (4096)
// ---------------------------------------------------------------------------
__global__ __launch_bounds__(256) void cvt_all(
    const float* __restrict__ a, const float* __restrict__ b, const float* __restrict__ c,
    const float* __restrict__ wa, const float* __restrict__ wb,
    const float* __restrict__ wc, const float* __restrict__ wd,
    unsigned short* __restrict__ oa, unsigned short* __restrict__ ob, unsigned short* __restrict__ oc,
    unsigned short* __restrict__ owa, unsigned short* __restrict__ owb,
    unsigned short* __restrict__ owc, unsigned short* __restrict__ owd)
{
    int bx = blockIdx.x;
    const float* in; unsigned short* out; int i;
    if (bx < 12288) {
        int which = bx >> 12;
        in  = which == 0 ? a : which == 1 ? b : c;
        out = which == 0 ? oa : which == 1 ? ob : oc;
        i = (bx & 4095) * 256 + threadIdx.x;
    } else {
        int b2 = bx - 12288;
        int which = b2 >> 10;
        in  = which == 0 ? wa : which == 1 ? wb : which == 2 ? wc : wd;
        out = which == 0 ? owa : which == 1 ? owb : which == 2 ? owc : owd;
        i = (b2 & 1023) * 256 + threadIdx.x;
    }
    float4 v = ((const float4*)in)[i];
    ushort4 o;
    o.x = f2bf(v.x); o.y = f2bf(v.y); o.z = f2bf(v.z); o.w = f2bf(v.w);
    ((ushort4*)out)[i] = o;
}

// ---------------------------------------------------------------------------
// Fused launch: QKV projection GEMMs (768 blocks) interleaved 3:16 with
// bias-prep blocks (4096 blocks). Grid = 19*256 = 4864. BW-bound prep waves
// co-reside with MFMA-bound GEMM waves -> memory/compute pipe overlap.
//
// GEMM part (m97-shape): C[4096,1024] = X @ W^T + bvec, 128x128 tile, BK=32.
//   z=0: Q-proj -> bf16, *0.125, zero masked rows
//   z=1: K-proj -> bf16 row-major
//   z=2: V-proj -> bf16 transposed [(b*1024+n)][s]
// Prep part: [B,S,S,H] f32 bias -> bf16 C-fragment-ordered tiles with mask
//   and /8 folded in (identical to previous prep_bias).
// ---------------------------------------------------------------------------
__global__ __launch_bounds__(256, 2) void qkv_prep(
    const unsigned short* __restrict__ X0, const unsigned short* __restrict__ X1,
    const unsigned short* __restrict__ X2,
    const unsigned short* __restrict__ W0, const unsigned short* __restrict__ W1,
    const unsigned short* __restrict__ W2,
    const float* __restrict__ bv0, const float* __restrict__ bv1,
    const float* __restrict__ bv2,
    unsigned short* __restrict__ Y0, unsigned short* __restrict__ Y1,
    unsigned short* __restrict__ Y2,
    const float* __restrict__ bias, const int* __restrict__ mask,
    unsigned short* __restrict__ biasP)
{
    __shared__ unsigned short As[128 * 32];
    __shared__ unsigned short Bs[128 * 32];

    const int t = threadIdx.x;
    const int bid = blockIdx.x;
    const int grp = bid / 19, rr = bid - grp * 19;

    if (rr < 3) {
        // ---------------- GEMM block ----------------
        const int gi = grp * 3 + rr;          // 0..767
        const int z = gi >> 8;                // 0..2
        const int rem = gi & 255;
        const int n0 = (rem & 7) * 128, m0 = (rem >> 3) * 128;

        const unsigned short* X = z == 0 ? X0 : z == 1 ? X1 : X2;
        const unsigned short* W = z == 0 ? W0 : z == 1 ? W1 : W2;
        const float* bvec = z == 0 ? bv0 : z == 1 ? bv1 : bv2;
        unsigned short* Y = z == 0 ? Y0 : z == 1 ? Y1 : Y2;

        const int w = t >> 6, l = t & 63;
        const int lane16 = l & 15, quad = l >> 4;
        const int wr = w >> 1, wc = w & 1;

        const int srow = w * 16 + (l >> 2);
        const unsigned short* agp = X + (size_t)(m0 + srow) * 1024 + (l & 3) * 8;
        const unsigned short* bgp = W + (size_t)(n0 + srow) * 1024 + (l & 3) * 8;
        unsigned short* alp = As + w * 512 + l * 8;
        unsigned short* blp = Bs + w * 512 + l * 8;

        f32x4 zero = {0.f, 0.f, 0.f, 0.f};
        f32x4 acc[4][4];
        #pragma unroll
        for (int i = 0; i < 4; ++i)
            #pragma unroll
            for (int j = 0; j < 4; ++j) acc[i][j] = zero;

        for (int kt = 0; kt < 1024; kt += 32) {
            GLDS(agp + kt, alp);
            GLDS(agp + kt + 64 * 1024, alp + 2048);
            GLDS(bgp + kt, blp);
            GLDS(bgp + kt + 64 * 1024, blp + 2048);
            __syncthreads();

            bf16x8 af[4], bfv[4];
            #pragma unroll
            for (int i = 0; i < 4; ++i)
                af[i] = *(const bf16x8*)(As + (wr * 64 + i * 16 + lane16) * 32 + quad * 8);
            #pragma unroll
            for (int j = 0; j < 4; ++j)
                bfv[j] = *(const bf16x8*)(Bs + (wc * 64 + j * 16 + lane16) * 32 + quad * 8);

            #pragma unroll
            for (int i = 0; i < 4; ++i)
                #pragma unroll
                for (int j = 0; j < 4; ++j)
                    acc[i][j] = MFMA(af[i], bfv[j], acc[i][j]);
            __syncthreads();
        }

        float bvl[4];
        #pragma unroll
        for (int j = 0; j < 4; ++j) bvl[j] = bvec[n0 + wc * 64 + j * 16 + lane16];

        if (z == 2) {
            // V transposed: out[(b*1024+n)][s], pack 4 consecutive s
            const int bb = m0 >> 10;
            const int sb = (m0 & 1023) + wr * 64;
            #pragma unroll
            for (int i = 0; i < 4; ++i) {
                #pragma unroll
                for (int j = 0; j < 4; ++j) {
                    int n = n0 + wc * 64 + j * 16 + lane16;
                    ushort4 pk;
                    pk.x = f2bf(acc[i][j][0] + bvl[j]);
                    pk.y = f2bf(acc[i][j][1] + bvl[j]);
                    pk.z = f2bf(acc[i][j][2] + bvl[j]);
                    pk.w = f2bf(acc[i][j][3] + bvl[j]);
                    int s = sb + i * 16 + quad * 4;
                    *(ushort4*)(Y + ((size_t)(bb * 1024 + n)) * 1024 + s) = pk;
                }
            }
        } else {
            #pragma unroll
            for (int i = 0; i < 4; ++i) {
                int mrow[4];
                #pragma unroll
                for (int r = 0; r < 4; ++r)
                    mrow[r] = (z == 0) ? mask[m0 + wr * 64 + i * 16 + quad * 4 + r] : 1;
                #pragma unroll
                for (int j = 0; j < 4; ++j) {
                    int n = n0 + wc * 64 + j * 16 + lane16;
                    #pragma unroll
                    for (int r = 0; r < 4; ++r) {
                        size_t m = m0 + wr * 64 + i * 16 + quad * 4 + r;
                        float val = acc[i][j][r] + bvl[j];
                        if (z == 0) val = mrow[r] ? val * 0.125f : 0.f;
                        Y[m * 1024 + n] = f2bf(val);
                    }
                }
            }
        }
    } else {
        // ---------------- bias-prep block ----------------
        const int pidx = grp * 16 + (rr - 3);     // 0..4095
        const int hh = t & 15, u = t >> 4;
        const int kt = pidx & 15, q16 = (pidx >> 4) & 63, bb = pidx >> 10;

        const unsigned short NEG = f2bf(-28672.f);

        int mk[4];
        #pragma unroll
        for (int j = 0; j < 4; ++j) mk[j] = mask[bb * 1024 + kt * 64 + j * 16 + u];

        const float* bbp = bias + (((size_t)(bb * 1024 + q16 * 16) * 1024) + kt * 64) * 16 + hh;
        unsigned short* obp = biasP + ((((size_t)(bb * 16 + hh) * 64 + q16) * 16 + kt) * 64) * 16;

        #pragma unroll
        for (int quad = 0; quad < 4; ++quad) {
            bf16x8 v0, v1;
            #pragma unroll
            for (int r = 0; r < 4; ++r) {
                int q = quad * 4 + r;
                int mq = mask[bb * 1024 + q16 * 16 + q];  // wave-uniform -> s_load
                #pragma unroll
                for (int j = 0; j < 4; ++j) {
                    float v = bbp[((size_t)q * 1024 + j * 16 + u) * 16];
                    unsigned short pv = (mq && mk[j]) ? f2bf(v * 0.125f) : NEG;
                    if (j < 2) v0[j * 4 + r] = (short)pv;
                    else       v1[(j - 2) * 4 + r] = (short)pv;
                }
            }
            unsigned short* dst = obp + (size_t)(quad * 16 + u) * 16;
            *(bf16x8*)(dst) = v0;
            *(bf16x8*)(dst + 8) = v1;
        }
    }
}

// ---------------------------------------------------------------------------
// MFMA flash attention, double-buffered K/V, ONE barrier per k-tile.
// Block = (b,h,64 q), 4 waves x 16 q rows. LDS = 16K K + 16K V + 8K Ps = 40 KB
// exactly -> 4 blocks/CU. Ps is stride-64 with XOR swizzle (byte^=(row&7)<<4).
// Tile t+1 GLDS issued right after the barrier publishing tile t, so the
// compiler's vmcnt(0)-before-barrier drain lands after a full compute phase.
// Bias fragment for t+1 prefetched mid-iteration.
// ---------------------------------------------------------------------------
__global__ __launch_bounds__(256, 2) void attn_mfma(
    const unsigned short* __restrict__ Qp, const unsigned short* __restrict__ Kp,
    const unsigned short* __restrict__ VpT, const unsigned short* __restrict__ biasP,
    unsigned short* __restrict__ Xp)
{
    __shared__ unsigned short Ks[2][64 * 64];
    __shared__ unsigned short Vs[2][64 * 64];
    __shared__ unsigned short Ps[4][16 * 64];

    const int t = threadIdx.x;
    const int w = t >> 6, l = t & 63;
    const int lane16 = l & 15, quad = l >> 4;

    const int bid = blockIdx.x;
    const int bh = bid & 63, qt = bid >> 6;
    const int h = bh & 15, b = bh >> 4;
    const int q0 = qt * 64;
    const int qrow0 = q0 + w * 16;
    const int q16 = qt * 4 + w;

    // Q fragments (bf16, pre-scaled)
    bf16x8 qf[2];
    #pragma unroll
    for (int c = 0; c < 2; ++c)
        qf[c] = *(const bf16x8*)(Qp + (size_t)(b * 1024 + qrow0 + lane16) * 1024
                                 + h * 64 + c * 32 + quad * 8);

    // bias fragment base for this wave/lane
    const unsigned short* bp = biasP
        + ((((size_t)(b * 16 + h) * 64 + q16) * 16) * 64 + l) * 16;

    // K/V staging (xor-swizzled 16B granules within 128B rows)
    const int krow = w * 8 + (l >> 3);
    const int kgran = (l & 7) ^ ((l >> 3) & 7);
    const unsigned short* kg = Kp + (size_t)(b * 1024 + krow) * 1024 + h * 64 + kgran * 8;
    const unsigned short* vg = VpT + ((size_t)(b * 16 + h) * 64 + krow) * 1024 + kgran * 8;
    unsigned short* kst = &Ks[0][w * 512 + l * 8];
    unsigned short* vst = &Vs[0][w * 512 + l * 8];

    // prologue: stage tile 0 into buffer 0, load bias frag 0
    GLDS(kg, kst);
    GLDS(kg + (size_t)32 * 1024, kst + 32 * 64);
    GLDS(vg, vst);
    GLDS(vg + (size_t)32 * 1024, vst + 32 * 64);
    bf16x8 bfr0 = *(const bf16x8*)(bp);
    bf16x8 bfr1 = *(const bf16x8*)(bp + 8);

    f32x4 zero = {0.f, 0.f, 0.f, 0.f};
    f32x4 o[4];
    #pragma unroll
    for (int j = 0; j < 4; ++j) o[j] = zero;
    float m_i[4] = {-1e30f, -1e30f, -1e30f, -1e30f};
    float l_i[4] = {0.f, 0.f, 0.f, 0.f};

    char* psb = (char*)&Ps[w][0];

    for (int kt16 = 0; kt16 < 16; ++kt16) {
        const int cur = kt16 & 1;
        __syncthreads();    // publishes tile kt16 (+ drains in-flight prefetch)

        // prefetch tile kt16+1 into the other buffer (uniform branch)
        if (kt16 < 15) {
            const size_t kn = (size_t)(kt16 + 1) * 64;
            unsigned short* kd = kst + (cur ^ 1) * 4096;
            unsigned short* vd = vst + (cur ^ 1) * 4096;
            GLDS(kg + kn * 1024, kd);
            GLDS(kg + (kn + 32) * 1024, kd + 32 * 64);
            GLDS(vg + kn, vd);
            GLDS(vg + kn + (size_t)32 * 1024, vd + 32 * 64);
        }

        const unsigned short* Kc = &Ks[0][0] + cur * 4096;
        const unsigned short* Vc = &Vs[0][0] + cur * 4096;

        // S = Q K^T
        f32x4 s[4];
        #pragma unroll
        for (int j = 0; j < 4; ++j) {
            s[j] = zero;
            #pragma unroll
            for (int c = 0; c < 2; ++c) {
                bf16x8 kf = *(const bf16x8*)(Kc + (j * 16 + lane16) * 64
                                             + (((c * 4 + quad) ^ (lane16 & 7)) * 8));
                s[j] = MFMA(qf[c], kf, s[j]);
            }
        }

        // add prepped bias (mask & scale already folded)
        #pragma unroll
        for (int e = 0; e < 8; ++e) {
            s[e >> 2][e & 3]       += bf2f((unsigned short)bfr0[e]);
            s[2 + (e >> 2)][e & 3] += bf2f((unsigned short)bfr1[e]);
        }

        // prefetch bias fragment for next tile (drained at next barrier)
        if (kt16 < 15) {
            bfr0 = *(const bf16x8*)(bp + (size_t)(kt16 + 1) * 1024);
            bfr1 = *(const bf16x8*)(bp + (size_t)(kt16 + 1) * 1024 + 8);
        }

        // online softmax
        float p[4][4];
        #pragma unroll
        for (int r = 0; r < 4; ++r) {
            float mx = fmaxf(fmaxf(s[0][r], s[1][r]), fmaxf(s[2][r], s[3][r]));
            #pragma unroll
            for (int d = 1; d < 16; d <<= 1) mx = fmaxf(mx, __shfl_xor(mx, d, 64));
            float mnew = fmaxf(m_i[r], mx);
            float alpha = __expf(m_i[r] - mnew);
            m_i[r] = mnew;
            float sum = 0.f;
            #pragma unroll
            for (int j = 0; j < 4; ++j) {
                p[j][r] = __expf(s[j][r] - mnew);
                sum += p[j][r];
            }
            #pragma unroll
            for (int d = 1; d < 16; d <<= 1) sum += __shfl_xor(sum, d, 64);
            l_i[r] = l_i[r] * alpha + sum;
            #pragma unroll
            for (int jd = 0; jd < 4; ++jd) o[jd][r] *= alpha;
        }

        // P: C-layout -> LDS (XOR-swizzled stride-64) -> A-layout (intra-wave)
        #pragma unroll
        for (int j = 0; j < 4; ++j)
            #pragma unroll
            for (int r = 0; r < 4; ++r) {
                int row = quad * 4 + r;
                int cb = (j * 16 + lane16) * 2;
                *(unsigned short*)(psb + row * 128 + (cb ^ ((row & 7) << 4))) = f2bf(p[j][r]);
            }
        asm volatile("" ::: "memory");

        bf16x8 pf[2];
        #pragma unroll
        for (int c = 0; c < 2; ++c) {
            int cb = c * 64 + quad * 16;
            pf[c] = *(const bf16x8*)(psb + lane16 * 128 + (cb ^ ((lane16 & 7) << 4)));
        }

        // O += P V
        #pragma unroll
        for (int jd = 0; jd < 4; ++jd)
            #pragma unroll
            for (int c = 0; c < 2; ++c) {
                bf16x8 vf = *(const bf16x8*)(Vc + (jd * 16 + lane16) * 64
                                             + (((c * 4 + quad) ^ (lane16 & 7)) * 8));
                o[jd] = MFMA(pf[c], vf, o[jd]);
            }
        // no trailing barrier: next top-barrier protects buffer reuse
    }

    float inv[4];
    #pragma unroll
    for (int r = 0; r < 4; ++r) inv[r] = 1.0f / l_i[r];

    #pragma unroll
    for (int jd = 0; jd < 4; ++jd)
        #pragma unroll
        for (int r = 0; r < 4; ++r)
            Xp[(size_t)(b * 1024 + qrow0 + quad * 4 + r) * 1024
               + h * 64 + jd * 16 + lane16] = f2bf(o[jd][r] * inv[r]);
}

// ---------------------------------------------------------------------------
// O-projection GEMM, 128x64 tile -> 512 blocks (2 blocks/CU for cross-block
// latency hiding; the 128x128 version only reached 1 block/CU at 256 blocks).
// C[4096,1024] f32 = X(bf16) @ W^T + b. 4 waves as 2x2 of 64x32.
// ---------------------------------------------------------------------------
__global__ __launch_bounds__(256, 2) void gemm_o64(
    const unsigned short* __restrict__ X, const unsigned short* __restrict__ W,
    const float* __restrict__ bvec, float* __restrict__ Y)
{
    __shared__ unsigned short As[128 * 32];
    __shared__ unsigned short Bs[64 * 32];

    const int t = threadIdx.x;
    const int w = t >> 6, l = t & 63;
    const int lane16 = l & 15, quad = l >> 4;
    const int m0 = blockIdx.y * 128, n0 = blockIdx.x * 64;
    const int wr = w >> 1, wc = w & 1;

    const int srow = w * 16 + (l >> 2);                 // 0..63
    const unsigned short* agp = X + (size_t)(m0 + srow) * 1024 + (l & 3) * 8;
    const unsigned short* bgp = W + (size_t)(n0 + srow) * 1024 + (l & 3) * 8;
    unsigned short* alp = As + w * 512 + l * 8;
    unsigned short* blp = Bs + w * 512 + l * 8;

    f32x4 zero = {0.f, 0.f, 0.f, 0.f};
    f32x4 acc[4][2];
    #pragma unroll
    for (int i = 0; i < 4; ++i)
        #pragma unroll
        for (int j = 0; j < 2; ++j) acc[i][j] = zero;

    for (int kt = 0; kt < 1024; kt += 32) {
        GLDS(agp + kt, alp);
        GLDS(agp + kt + 64 * 1024, alp + 2048);
        GLDS(bgp + kt, blp);
        __syncthreads();

        bf16x8 af[4], bfv[2];
        #pragma unroll
        for (int i = 0; i < 4; ++i)
            af[i] = *(const bf16x8*)(As + (wr * 64 + i * 16 + lane16) * 32 + quad * 8);
        #pragma unroll
        for (int j = 0; j < 2; ++j)
            bfv[j] = *(const bf16x8*)(Bs + (wc * 32 + j * 16 + lane16) * 32 + quad * 8);

        #pragma unroll
        for (int i = 0; i < 4; ++i)
            #pragma unroll
            for (int j = 0; j < 2; ++j)
                acc[i][j] = MFMA(af[i], bfv[j], acc[i][j]);
        __syncthreads();
    }

    float bvl[2];
    #pragma unroll
    for (int j = 0; j < 2; ++j) bvl[j] = bvec[n0 + wc * 32 + j * 16 + lane16];

    #pragma unroll
    for (int i = 0; i < 4; ++i)
        #pragma unroll
        for (int j = 0; j < 2; ++j) {
            int n = n0 + wc * 32 + j * 16 + lane16;
            #pragma unroll
            for (int r = 0; r < 4; ++r) {
                size_t m = m0 + wr * 64 + i * 16 + quad * 4 + r;
                Y[m * 1024 + n] = acc[i][j][r] + bvl[j];
            }
        }
}

// ---------------------------------------------------------------------------
extern "C" void kernel_launch(void* const* d_in, const int* in_sizes, int n_in,
                              void* d_out, int out_size, void* d_ws, size_t ws_size,
                              hipStream_t stream)
{
    const float* query = (const float*)d_in[0];
    const float* key   = (const float*)d_in[1];
    const float* value = (const float*)d_in[2];
    const float* abias = (const float*)d_in[3];
    const int*   mask  = (const int*)d_in[4];
    const float* Wq = (const float*)d_in[5];
    const float* bq = (const float*)d_in[6];
    const float* Wk = (const float*)d_in[7];
    const float* bk = (const float*)d_in[8];
    const float* Wv = (const float*)d_in[9];
    const float* bv = (const float*)d_in[10];
    const float* Wo = (const float*)d_in[11];
    const float* bo = (const float*)d_in[12];
    float* out = (float*)d_out;

    const size_t T = (size_t)B_ * S_ * D_;           // 4 Mi
    const size_t WSZ = (size_t)D_ * D_;              // 1 Mi
    const size_t BPSZ = (size_t)B_ * H_ * S_ * S_;   // 64 Mi
    unsigned short* p = (unsigned short*)d_ws;
    unsigned short* biasP = p;  p += BPSZ;
    unsigned short* qb  = p;  p += T;
    unsigned short* kb  = p;  p += T;
    unsigned short* vb  = p;  p += T;
    unsigned short* wqb = p;  p += WSZ;
    unsigned short* wkb = p;  p += WSZ;
    unsigned short* wvb = p;  p += WSZ;
    unsigned short* wob = p;  p += WSZ;
    unsigned short* Qpj = p;  p += T;
    unsigned short* Kpj = p;  p += T;
    unsigned short* VpT = p;  p += T;
    unsigned short* Xpj = p;  p += T;

    cvt_all<<<dim3(16384), 256, 0, stream>>>(
        query, key, value, Wq, Wk, Wv, Wo,
        qb, kb, vb, wqb, wkb, wvb, wob);

    // fused: QKV projections (768 blocks) interleaved 3:16 with bias prep (4096)
    qkv_prep<<<dim3(4864), 256, 0, stream>>>(
        qb, kb, vb, wqb, wkb, wvb, bq, bk, bv,
        Qpj, Kpj, VpT, abias, mask, biasP);

    attn_mfma<<<dim3(1024), 256, 0, stream>>>(Qpj, Kpj, VpT, biasP, Xpj);

    gemm_o64<<<dim3(16, 32), 256, 0, stream>>>(Xpj, wob, bo, out);
}

// Round 4
// 561.384 us; speedup vs baseline: 1.0718x; 1.0718x over previous
//
#include <hip/hip_runtime.h>
#include <hip/hip_bf16.h>
#include <math.h>

#define B_ 4
#define S_ 1024
#define D_ 1024
#define H_ 16
#define DK_ 64

typedef short bf16x8 __attribute__((ext_vector_type(8)));
typedef float f32x4 __attribute__((ext_vector_type(4)));

#define MFMA(a, b, c) __builtin_amdgcn_mfma_f32_16x16x32_bf16(a, b, c, 0, 0, 0)

// async global->LDS, 16B per lane. Effective LDS dest = wave-uniform base + lane*16.
#define GLDS(gp, lp)                                                        \
    __builtin_amdgcn_global_load_lds(                                       \
        (const __attribute__((address_space(1))) void*)(const void*)(gp),   \
        (__attribute__((address_space(3))) void*)(void*)(lp), 16, 0, 0)

static __device__ __forceinline__ unsigned short f2bf(float f) {
    __hip_bfloat16 h = __float2bfloat16(f);
    return *reinterpret_cast<unsigned short*>(&h);
}
static __device__ __forceinline__ float bf2f(unsigned short u) {
    unsigned int x = ((unsigned int)u) << 16;
    union { unsigned int i; float f; } c; c.i = x; return c.f;
}

// ---------------------------------------------------------------------------
// fused f32->bf16 converts: 3 activations (12288 blocks) + 4 weights (4096)
// ---------------------------------------------------------------------------
__global__ __launch_bounds__(256) void cvt_all(
    const float* __restrict__ a, const float* __restrict__ b, const float* __restrict__ c,
    const float* __restrict__ wa, const float* __restrict__ wb,
    const float* __restrict__ wc, const float* __restrict__ wd,
    unsigned short* __restrict__ oa, unsigned short* __restrict__ ob, unsigned short* __restrict__ oc,
    unsigned short* __restrict__ owa, unsigned short* __restrict__ owb,
    unsigned short* __restrict__ owc, unsigned short* __restrict__ owd)
{
    int bx = blockIdx.x;
    const float* in; unsigned short* out; int i;
    if (bx < 12288) {
        int which = bx >> 12;
        in  = which == 0 ? a : which == 1 ? b : c;
        out = which == 0 ? oa : which == 1 ? ob : oc;
        i = (bx & 4095) * 256 + threadIdx.x;
    } else {
        int b2 = bx - 12288;
        int which = b2 >> 10;
        in  = which == 0 ? wa : which == 1 ? wb : which == 2 ? wc : wd;
        out = which == 0 ? owa : which == 1 ? owb : which == 2 ? owc : owd;
        i = (b2 & 1023) * 256 + threadIdx.x;
    }
    float4 v = ((const float4*)in)[i];
    ushort4 o;
    o.x = f2bf(v.x); o.y = f2bf(v.y); o.z = f2bf(v.z); o.w = f2bf(v.w);
    ((ushort4*)out)[i] = o;
}

// ---------------------------------------------------------------------------
// bias prep (standalone, high-occupancy BW kernel — fusing it with the GEMM
// was a measured regression: both pipes idled at 22% HBM / 5% MFMA).
// [B,S,S,H] f32 -> bf16 C-fragment-ordered tiles, with mask + /8 folded in.
// ---------------------------------------------------------------------------
__global__ __launch_bounds__(256) void prep_bias(
    const float* __restrict__ bias, const int* __restrict__ mask,
    unsigned short* __restrict__ biasP)
{
    const int t = threadIdx.x;
    const int h = t & 15, u = t >> 4;
    const int x = blockIdx.x;
    const int kt = x & 15, q16 = (x >> 4) & 63, b = x >> 10;

    const unsigned short NEG = f2bf(-28672.f);

    int mk[4];
    #pragma unroll
    for (int j = 0; j < 4; ++j) mk[j] = mask[b * 1024 + kt * 64 + j * 16 + u];

    const float* bb = bias + (((size_t)(b * 1024 + q16 * 16) * 1024) + kt * 64) * 16 + h;
    unsigned short* ob = biasP + ((((size_t)(b * 16 + h) * 64 + q16) * 16 + kt) * 64) * 16;

    #pragma unroll
    for (int quad = 0; quad < 4; ++quad) {
        bf16x8 v0, v1;
        #pragma unroll
        for (int r = 0; r < 4; ++r) {
            int q = quad * 4 + r;
            int mq = mask[b * 1024 + q16 * 16 + q];  // wave-uniform -> s_load
            #pragma unroll
            for (int j = 0; j < 4; ++j) {
                float v = bb[((size_t)q * 1024 + j * 16 + u) * 16];
                unsigned short pv = (mq && mk[j]) ? f2bf(v * 0.125f) : NEG;
                if (j < 2) v0[j * 4 + r] = (short)pv;
                else       v1[(j - 2) * 4 + r] = (short)pv;
            }
        }
        unsigned short* dst = ob + (size_t)(quad * 16 + u) * 16;
        *(bf16x8*)(dst) = v0;
        *(bf16x8*)(dst + 8) = v1;
    }
}

// ---------------------------------------------------------------------------
// m97-shape bf16 MFMA GEMM for QKV projections: C[4096,1024] = X @ W^T + bvec.
// Tile 128x128, BK=32, 4 waves of 64x64. blockIdx.z selects (X,W,b,Y).
// z=0: Q-proj -> bf16, *0.125, zero masked rows
// z=1: K-proj -> bf16 row-major
// z=2: V-proj -> bf16 transposed [(b*1024+n)][s]
// ---------------------------------------------------------------------------
__global__ __launch_bounds__(256, 2) void gemm128(
    const unsigned short* __restrict__ X0, const unsigned short* __restrict__ X1,
    const unsigned short* __restrict__ X2,
    const unsigned short* __restrict__ W0, const unsigned short* __restrict__ W1,
    const unsigned short* __restrict__ W2,
    const float* __restrict__ bv0, const float* __restrict__ bv1,
    const float* __restrict__ bv2,
    unsigned short* __restrict__ Y0, unsigned short* __restrict__ Y1,
    unsigned short* __restrict__ Y2,
    const int* __restrict__ mask)
{
    __shared__ unsigned short As[128 * 32];
    __shared__ unsigned short Bs[128 * 32];

    const int z = blockIdx.z;
    const unsigned short* X = z == 0 ? X0 : z == 1 ? X1 : X2;
    const unsigned short* W = z == 0 ? W0 : z == 1 ? W1 : W2;
    const float* bvec = z == 0 ? bv0 : z == 1 ? bv1 : bv2;
    unsigned short* Y = z == 0 ? Y0 : z == 1 ? Y1 : Y2;

    const int t = threadIdx.x;
    const int w = t >> 6, l = t & 63;
    const int lane16 = l & 15, quad = l >> 4;
    const int m0 = blockIdx.y * 128, n0 = blockIdx.x * 128;
    const int wr = w >> 1, wc = w & 1;

    const int srow = w * 16 + (l >> 2);
    const unsigned short* agp = X + (size_t)(m0 + srow) * 1024 + (l & 3) * 8;
    const unsigned short* bgp = W + (size_t)(n0 + srow) * 1024 + (l & 3) * 8;
    unsigned short* alp = As + w * 512 + l * 8;
    unsigned short* blp = Bs + w * 512 + l * 8;

    f32x4 zero = {0.f, 0.f, 0.f, 0.f};
    f32x4 acc[4][4];
    #pragma unroll
    for (int i = 0; i < 4; ++i)
        #pragma unroll
        for (int j = 0; j < 4; ++j) acc[i][j] = zero;

    for (int kt = 0; kt < 1024; kt += 32) {
        GLDS(agp + kt, alp);
        GLDS(agp + kt + 64 * 1024, alp + 2048);
        GLDS(bgp + kt, blp);
        GLDS(bgp + kt + 64 * 1024, blp + 2048);
        __syncthreads();

        bf16x8 af[4], bfv[4];
        #pragma unroll
        for (int i = 0; i < 4; ++i)
            af[i] = *(const bf16x8*)(As + (wr * 64 + i * 16 + lane16) * 32 + quad * 8);
        #pragma unroll
        for (int j = 0; j < 4; ++j)
            bfv[j] = *(const bf16x8*)(Bs + (wc * 64 + j * 16 + lane16) * 32 + quad * 8);

        #pragma unroll
        for (int i = 0; i < 4; ++i)
            #pragma unroll
            for (int j = 0; j < 4; ++j)
                acc[i][j] = MFMA(af[i], bfv[j], acc[i][j]);
        __syncthreads();
    }

    float bvl[4];
    #pragma unroll
    for (int j = 0; j < 4; ++j) bvl[j] = bvec[n0 + wc * 64 + j * 16 + lane16];

    if (z == 2) {
        // V transposed: out[(b*1024+n)][s], pack 4 consecutive s
        const int bb = m0 >> 10;
        const int sb = (m0 & 1023) + wr * 64;
        #pragma unroll
        for (int i = 0; i < 4; ++i) {
            #pragma unroll
            for (int j = 0; j < 4; ++j) {
                int n = n0 + wc * 64 + j * 16 + lane16;
                ushort4 pk;
                pk.x = f2bf(acc[i][j][0] + bvl[j]);
                pk.y = f2bf(acc[i][j][1] + bvl[j]);
                pk.z = f2bf(acc[i][j][2] + bvl[j]);
                pk.w = f2bf(acc[i][j][3] + bvl[j]);
                int s = sb + i * 16 + quad * 4;
                *(ushort4*)(Y + ((size_t)(bb * 1024 + n)) * 1024 + s) = pk;
            }
        }
    } else {
        #pragma unroll
        for (int i = 0; i < 4; ++i) {
            int mrow[4];
            #pragma unroll
            for (int r = 0; r < 4; ++r)
                mrow[r] = (z == 0) ? mask[m0 + wr * 64 + i * 16 + quad * 4 + r] : 1;
            #pragma unroll
            for (int j = 0; j < 4; ++j) {
                int n = n0 + wc * 64 + j * 16 + lane16;
                #pragma unroll
                for (int r = 0; r < 4; ++r) {
                    size_t m = m0 + wr * 64 + i * 16 + quad * 4 + r;
                    float val = acc[i][j][r] + bvl[j];
                    if (z == 0) val = mrow[r] ? val * 0.125f : 0.f;
                    Y[m * 1024 + n] = f2bf(val);
                }
            }
        }
    }
}

// ---------------------------------------------------------------------------
// MFMA flash attention, double-buffered K/V, ONE barrier per k-tile.
// Block = (b,h,64 q), 4 waves x 16 q rows. LDS = 40 KB -> 4 blocks/CU.
//  - bias fragment used as MFMA C-init (saves the add-after pass)
//  - row-sum l via MFMA with an all-ones B operand (replaces 16-lane shfl
//    sum tree; D row = quad*4+r matches l_i[r] indexing)
//  - s_setprio(1) around MFMA clusters (T5 — measured +4-7% on attn)
// ---------------------------------------------------------------------------
__global__ __launch_bounds__(256, 2) void attn_mfma(
    const unsigned short* __restrict__ Qp, const unsigned short* __restrict__ Kp,
    const unsigned short* __restrict__ VpT, const unsigned short* __restrict__ biasP,
    unsigned short* __restrict__ Xp)
{
    __shared__ unsigned short Ks[2][64 * 64];
    __shared__ unsigned short Vs[2][64 * 64];
    __shared__ unsigned short Ps[4][16 * 64];

    const int t = threadIdx.x;
    const int w = t >> 6, l = t & 63;
    const int lane16 = l & 15, quad = l >> 4;

    const int bid = blockIdx.x;
    const int bh = bid & 63, qt = bid >> 6;
    const int h = bh & 15, b = bh >> 4;
    const int qrow0 = qt * 64 + w * 16;
    const int q16 = qt * 4 + w;

    // Q fragments (bf16, pre-scaled by 0.125; masked rows zeroed)
    bf16x8 qf[2];
    #pragma unroll
    for (int c = 0; c < 2; ++c)
        qf[c] = *(const bf16x8*)(Qp + (size_t)(b * 1024 + qrow0 + lane16) * 1024
                                 + h * 64 + c * 32 + quad * 8);

    // all-ones bf16 fragment for row-sum MFMA
    bf16x8 ones;
    #pragma unroll
    for (int e = 0; e < 8; ++e) ones[e] = (short)0x3F80;

    // bias fragment base for this wave/lane
    const unsigned short* bp = biasP
        + ((((size_t)(b * 16 + h) * 64 + q16) * 16) * 64 + l) * 16;

    // K/V staging (xor-swizzled 16B granules within 128B rows)
    const int krow = w * 8 + (l >> 3);
    const int kgran = (l & 7) ^ ((l >> 3) & 7);
    const unsigned short* kg = Kp + (size_t)(b * 1024 + krow) * 1024 + h * 64 + kgran * 8;
    const unsigned short* vg = VpT + ((size_t)(b * 16 + h) * 64 + krow) * 1024 + kgran * 8;
    unsigned short* kst = &Ks[0][w * 512 + l * 8];
    unsigned short* vst = &Vs[0][w * 512 + l * 8];

    // prologue: stage tile 0 into buffer 0, load bias frag 0
    GLDS(kg, kst);
    GLDS(kg + (size_t)32 * 1024, kst + 32 * 64);
    GLDS(vg, vst);
    GLDS(vg + (size_t)32 * 1024, vst + 32 * 64);
    bf16x8 bfr0 = *(const bf16x8*)(bp);
    bf16x8 bfr1 = *(const bf16x8*)(bp + 8);

    f32x4 zero = {0.f, 0.f, 0.f, 0.f};
    f32x4 o[4];
    #pragma unroll
    for (int j = 0; j < 4; ++j) o[j] = zero;
    float m_i[4] = {-1e30f, -1e30f, -1e30f, -1e30f};
    float l_i[4] = {0.f, 0.f, 0.f, 0.f};

    char* psb = (char*)&Ps[w][0];

    for (int kt16 = 0; kt16 < 16; ++kt16) {
        const int cur = kt16 & 1;
        __syncthreads();    // publishes tile kt16 (drains in-flight prefetch)

        // prefetch tile kt16+1 into the other buffer (uniform branch)
        if (kt16 < 15) {
            const size_t kn = (size_t)(kt16 + 1) * 64;
            unsigned short* kd = kst + (cur ^ 1) * 4096;
            unsigned short* vd = vst + (cur ^ 1) * 4096;
            GLDS(kg + kn * 1024, kd);
            GLDS(kg + (kn + 32) * 1024, kd + 32 * 64);
            GLDS(vg + kn, vd);
            GLDS(vg + kn + (size_t)32 * 1024, vd + 32 * 64);
        }

        const unsigned short* Kc = &Ks[0][0] + cur * 4096;
        const unsigned short* Vc = &Vs[0][0] + cur * 4096;

        // S = bias + Q K^T  (bias as accumulator init)
        f32x4 s[4];
        #pragma unroll
        for (int j = 0; j < 2; ++j)
            #pragma unroll
            for (int r = 0; r < 4; ++r) {
                s[j][r]     = bf2f((unsigned short)bfr0[j * 4 + r]);
                s[2 + j][r] = bf2f((unsigned short)bfr1[j * 4 + r]);
            }

        __builtin_amdgcn_s_setprio(1);
        #pragma unroll
        for (int j = 0; j < 4; ++j) {
            #pragma unroll
            for (int c = 0; c < 2; ++c) {
                bf16x8 kf = *(const bf16x8*)(Kc + (j * 16 + lane16) * 64
                                             + (((c * 4 + quad) ^ (lane16 & 7)) * 8));
                s[j] = MFMA(qf[c], kf, s[j]);
            }
        }
        __builtin_amdgcn_s_setprio(0);

        // prefetch bias fragment for next tile
        if (kt16 < 15) {
            bfr0 = *(const bf16x8*)(bp + (size_t)(kt16 + 1) * 1024);
            bfr1 = *(const bf16x8*)(bp + (size_t)(kt16 + 1) * 1024 + 8);
        }

        // online softmax: max + rescale only (sum comes from MFMA below)
        float p[4][4];
        float alpha_r[4];
        #pragma unroll
        for (int r = 0; r < 4; ++r) {
            float mx = fmaxf(fmaxf(s[0][r], s[1][r]), fmaxf(s[2][r], s[3][r]));
            #pragma unroll
            for (int d = 1; d < 16; d <<= 1) mx = fmaxf(mx, __shfl_xor(mx, d, 64));
            float mnew = fmaxf(m_i[r], mx);
            float alpha = __expf(m_i[r] - mnew);
            m_i[r] = mnew;
            alpha_r[r] = alpha;
            #pragma unroll
            for (int j = 0; j < 4; ++j) p[j][r] = __expf(s[j][r] - mnew);
            #pragma unroll
            for (int jd = 0; jd < 4; ++jd) o[jd][r] *= alpha;
        }

        // P: C-layout -> LDS (XOR-swizzled stride-64) -> A-layout (intra-wave)
        #pragma unroll
        for (int j = 0; j < 4; ++j)
            #pragma unroll
            for (int r = 0; r < 4; ++r) {
                int row = quad * 4 + r;
                int cb = (j * 16 + lane16) * 2;
                *(unsigned short*)(psb + row * 128 + (cb ^ ((row & 7) << 4))) = f2bf(p[j][r]);
            }
        asm volatile("" ::: "memory");

        bf16x8 pf[2];
        #pragma unroll
        for (int c = 0; c < 2; ++c) {
            int cb = c * 64 + quad * 16;
            pf[c] = *(const bf16x8*)(psb + lane16 * 128 + (cb ^ ((lane16 & 7) << 4)));
        }

        // O += P V ; row-sum via ones-MFMA (D row = quad*4+r matches l_i[r])
        f32x4 lacc = zero;
        __builtin_amdgcn_s_setprio(1);
        #pragma unroll
        for (int jd = 0; jd < 4; ++jd)
            #pragma unroll
            for (int c = 0; c < 2; ++c) {
                bf16x8 vf = *(const bf16x8*)(Vc + (jd * 16 + lane16) * 64
                                             + (((c * 4 + quad) ^ (lane16 & 7)) * 8));
                o[jd] = MFMA(pf[c], vf, o[jd]);
            }
        #pragma unroll
        for (int c = 0; c < 2; ++c)
            lacc = MFMA(pf[c], ones, lacc);
        __builtin_amdgcn_s_setprio(0);

        #pragma unroll
        for (int r = 0; r < 4; ++r)
            l_i[r] = l_i[r] * alpha_r[r] + lacc[r];
        // no trailing barrier: next top-barrier protects buffer reuse
    }

    float inv[4];
    #pragma unroll
    for (int r = 0; r < 4; ++r) inv[r] = 1.0f / l_i[r];

    #pragma unroll
    for (int jd = 0; jd < 4; ++jd)
        #pragma unroll
        for (int r = 0; r < 4; ++r)
            Xp[(size_t)(b * 1024 + qrow0 + quad * 4 + r) * 1024
               + h * 64 + jd * 16 + lane16] = f2bf(o[jd][r] * inv[r]);
}

// ---------------------------------------------------------------------------
// O-projection GEMM, 128x64 tile -> 512 blocks (2 blocks/CU).
// C[4096,1024] f32 = X(bf16) @ W^T + b. 4 waves as 2x2 of 64x32.
// ---------------------------------------------------------------------------
__global__ __launch_bounds__(256, 2) void gemm_o64(
    const unsigned short* __restrict__ X, const unsigned short* __restrict__ W,
    const float* __restrict__ bvec, float* __restrict__ Y)
{
    __shared__ unsigned short As[128 * 32];
    __shared__ unsigned short Bs[64 * 32];

    const int t = threadIdx.x;
    const int w = t >> 6, l = t & 63;
    const int lane16 = l & 15, quad = l >> 4;
    const int m0 = blockIdx.y * 128, n0 = blockIdx.x * 64;
    const int wr = w >> 1, wc = w & 1;

    const int srow = w * 16 + (l >> 2);                 // 0..63
    const unsigned short* agp = X + (size_t)(m0 + srow) * 1024 + (l & 3) * 8;
    const unsigned short* bgp = W + (size_t)(n0 + srow) * 1024 + (l & 3) * 8;
    unsigned short* alp = As + w * 512 + l * 8;
    unsigned short* blp = Bs + w * 512 + l * 8;

    f32x4 zero = {0.f, 0.f, 0.f, 0.f};
    f32x4 acc[4][2];
    #pragma unroll
    for (int i = 0; i < 4; ++i)
        #pragma unroll
        for (int j = 0; j < 2; ++j) acc[i][j] = zero;

    for (int kt = 0; kt < 1024; kt += 32) {
        GLDS(agp + kt, alp);
        GLDS(agp + kt + 64 * 1024, alp + 2048);
        GLDS(bgp + kt, blp);
        __syncthreads();

        bf16x8 af[4], bfv[2];
        #pragma unroll
        for (int i = 0; i < 4; ++i)
            af[i] = *(const bf16x8*)(As + (wr * 64 + i * 16 + lane16) * 32 + quad * 8);
        #pragma unroll
        for (int j = 0; j < 2; ++j)
            bfv[j] = *(const bf16x8*)(Bs + (wc * 32 + j * 16 + lane16) * 32 + quad * 8);

        #pragma unroll
        for (int i = 0; i < 4; ++i)
            #pragma unroll
            for (int j = 0; j < 2; ++j)
                acc[i][j] = MFMA(af[i], bfv[j], acc[i][j]);
        __syncthreads();
    }

    float bvl[2];
    #pragma unroll
    for (int j = 0; j < 2; ++j) bvl[j] = bvec[n0 + wc * 32 + j * 16 + lane16];

    #pragma unroll
    for (int i = 0; i < 4; ++i)
        #pragma unroll
        for (int j = 0; j < 2; ++j) {
            int n = n0 + wc * 32 + j * 16 + lane16;
            #pragma unroll
            for (int r = 0; r < 4; ++r) {
                size_t m = m0 + wr * 64 + i * 16 + quad * 4 + r;
                Y[m * 1024 + n] = acc[i][j][r] + bvl[j];
            }
        }
}

// ---------------------------------------------------------------------------
extern "C" void kernel_launch(void* const* d_in, const int* in_sizes, int n_in,
                              void* d_out, int out_size, void* d_ws, size_t ws_size,
                              hipStream_t stream)
{
    const float* query = (const float*)d_in[0];
    const float* key   = (const float*)d_in[1];
    const float* value = (const float*)d_in[2];
    const float* abias = (const float*)d_in[3];
    const int*   mask  = (const int*)d_in[4];
    const float* Wq = (const float*)d_in[5];
    const float* bq = (const float*)d_in[6];
    const float* Wk = (const float*)d_in[7];
    const float* bk = (const float*)d_in[8];
    const float* Wv = (const float*)d_in[9];
    const float* bv = (const float*)d_in[10];
    const float* Wo = (const float*)d_in[11];
    const float* bo = (const float*)d_in[12];
    float* out = (float*)d_out;

    const size_t T = (size_t)B_ * S_ * D_;           // 4 Mi
    const size_t WSZ = (size_t)D_ * D_;              // 1 Mi
    const size_t BPSZ = (size_t)B_ * H_ * S_ * S_;   // 64 Mi
    unsigned short* p = (unsigned short*)d_ws;
    unsigned short* biasP = p;  p += BPSZ;
    unsigned short* qb  = p;  p += T;
    unsigned short* kb  = p;  p += T;
    unsigned short* vb  = p;  p += T;
    unsigned short* wqb = p;  p += WSZ;
    unsigned short* wkb = p;  p += WSZ;
    unsigned short* wvb = p;  p += WSZ;
    unsigned short* wob = p;  p += WSZ;
    unsigned short* Qpj = p;  p += T;
    unsigned short* Kpj = p;  p += T;
    unsigned short* VpT = p;  p += T;
    unsigned short* Xpj = p;  p += T;

    cvt_all<<<dim3(16384), 256, 0, stream>>>(
        query, key, value, Wq, Wk, Wv, Wo,
        qb, kb, vb, wqb, wkb, wvb, wob);

    prep_bias<<<dim3(4096), 256, 0, stream>>>(abias, mask, biasP);

    gemm128<<<dim3(8, 32, 3), 256, 0, stream>>>(
        qb, kb, vb, wqb, wkb, wvb, bq, bk, bv,
        Qpj, Kpj, VpT, mask);

    attn_mfma<<<dim3(1024), 256, 0, stream>>>(Qpj, Kpj, VpT, biasP, Xpj);

    gemm_o64<<<dim3(16, 32), 256, 0, stream>>>(Xpj, wob, bo, out);
}